// Round 16
// baseline (1441.176 us; speedup 1.0000x reference)
//
#include <hip/hip_runtime.h>

#define T_LEN 386
#define NSPAN 73920

typedef float v4f __attribute__((ext_vector_type(4)));

// ---- LLC ops (sc0 sc1: device scope) ----
__device__ inline void llc_load8(const float* p, v4f& a, v4f& b) {
    asm volatile("global_load_dwordx4 %0, %2, off sc0 sc1\n\t"
                 "global_load_dwordx4 %1, %2, off offset:16 sc0 sc1\n\t"
                 "s_waitcnt vmcnt(0)"
                 : "=&v"(a), "=&v"(b) : "v"(p) : "memory");
}
__device__ inline void llc_store1(float* p, float v) {
    asm volatile("global_store_dword %0, %1, off sc0 sc1"
                 :: "v"(p), "v"(v) : "memory");
}

__device__ inline float fsigmoid(float x) { return 1.f / (1.f + __expf(-x)); }
__device__ inline float ftanh(float x) {
    x = fminf(fmaxf(x, -15.f), 15.f);
    float e = __expf(2.f * x);
    return (e - 1.f) / (e + 1.f);
}

// ---------------- kernel 1: embedding concat + h-sentinel poison ----------------
// grid 386, 128 threads. Also poisons fwd/bwd (2*386*512 floats) with the
// unreachable sentinel 2.0f (h = o*tanh(c) is strictly inside (-1,1)):
// 386*128 threads * 8 floats = 395264 = 2*386*512 exactly.
__global__ void k_embed(const int* __restrict__ tag_ids, const int* __restrict__ word_ids,
                        const float* __restrict__ tag_emb, const float* __restrict__ word_emb,
                        float* __restrict__ x, float* __restrict__ st) {
    int t = blockIdx.x;
    int tid = threadIdx.x; // 128
    long pbase = ((long)t * 128 + tid) * 8;
#pragma unroll
    for (int j = 0; j < 8; ++j)
        __hip_atomic_store(st + pbase + j, 2.0f, __ATOMIC_RELAXED,
                           __HIP_MEMORY_SCOPE_AGENT);
    int tr = tag_ids[t], wr = word_ids[t];
    x[t * 512 + tid] = tag_emb[tr * 128 + tid];
    for (int j = tid; j < 384; j += 128)
        x[t * 512 + 128 + j] = word_emb[wr * 384 + j];
}

// ---------------- kernel 2: gx = x(rev) @ Wih^T + b ----------------
// grid (32 n-tiles, 25 t-tiles of 16, 2 dirs), block 256, 32KB LDS -> 5 blk/CU
__launch_bounds__(256, 5)
__global__ void k_gx(const float* __restrict__ x,
                     const float* __restrict__ Wf, const float* __restrict__ bf,
                     const float* __restrict__ Wb, const float* __restrict__ bb,
                     float* __restrict__ gxf, float* __restrict__ gxb) {
    __shared__ float xs[16 * 512];
    int dir = blockIdx.z;
    const float* W = dir ? Wb : Wf;
    const float* bias = dir ? bb : bf;
    float* out = dir ? gxb : gxf;
    int nbase = blockIdx.x * 64;
    int tbase = blockIdx.y * 16;
    int tid = threadIdx.x;

    for (int i = tid; i < 16 * 128; i += 256) { // float4 units
        int row = i >> 7, c4 = i & 127;
        int t = tbase + row;
        float4 v = make_float4(0.f, 0.f, 0.f, 0.f);
        if (t < T_LEN) {
            int src = dir ? (T_LEN - 1 - t) : t;
            v = ((const float4*)(x + src * 512))[c4];
        }
        ((float4*)xs)[i] = v;
    }
    __syncthreads();

    int col = tid >> 2; // 0..63
    int kq = tid & 3;
    int n = nbase + col;
    const float4* wrow = (const float4*)(W + (long)n * 512);
    float acc[16];
#pragma unroll
    for (int r = 0; r < 16; ++r) acc[r] = 0.f;
#pragma unroll 2
    for (int it = 0; it < 32; ++it) {
        int k4 = it * 4 + kq; // k = it*16 + kq*4
        float4 w = wrow[k4];
#pragma unroll
        for (int r = 0; r < 16; ++r) {
            float4 xv = ((const float4*)(xs + r * 512))[k4];
            acc[r] += w.x * xv.x + w.y * xv.y + w.z * xv.z + w.w * xv.w;
        }
    }
#pragma unroll
    for (int r = 0; r < 16; ++r) {
        float v = acc[r];
        v += __shfl_xor(v, 1, 4);
        v += __shfl_xor(v, 2, 4);
        acc[r] = v;
    }
    if (kq == 0) {
        float bv = bias[n];
        for (int r = 0; r < 16; ++r) {
            int t = tbase + r;
            if (t < T_LEN) out[t * 2048 + n] = acc[r] + bv;
        }
    }
}

// ---------------- kernel 3: persistent bidirectional LSTM scan (proven) ----------------
// grid 64 (2 dirs * 32 WGs), block 256, 1 WG/CU. Each WG owns 16 hidden units;
// a 16-lane group owns one unit (4 gates x 4 k-slices); Whh slice in regs,
// gx slice in LDS, cell state in regs. Cross-WG broadcast: data-as-flag
// (sentinel 2.0f) through the LLC. Measured floor: ~2.25us/step (LLC
// store->load visibility); XCD-L2 fast paths all failed on HW (R5/R7/R12).
__launch_bounds__(256, 1)
__global__ void k_scan(const float* __restrict__ gxf, const float* __restrict__ gxb,
                       const float* __restrict__ Wfhh, const float* __restrict__ Wbhh,
                       float* fwd, float* bwd) {
    __shared__ float gx_sh[T_LEN * 64];
    __shared__ float h_sh[2][512];
    int bid = blockIdx.x;
    int dir = bid >> 5;
    int w = bid & 31;
    int tid = threadIdx.x;
    const float* gx = dir ? gxb : gxf;
    const float* Whh = dir ? Wbhh : Wfhh;
    float* st = dir ? bwd : fwd;

    for (int idx = tid; idx < T_LEN * 64; idx += 256) {
        int t = idx >> 6, j = idx & 63;
        gx_sh[idx] = gx[t * 2048 + (j >> 4) * 512 + w * 16 + (j & 15)];
    }

    int u = tid >> 4;  // hidden unit 0..15
    int r = tid & 15;  // lane-in-unit
    int g = r >> 2;    // gate 0..3 (i,f,g,o)
    int kq = r & 3;    // k-slice
    int grow = g * 512 + w * 16 + u;
    float4 wreg[32];
    const float4* wsrc = (const float4*)(Whh + (long)grow * 512);
#pragma unroll
    for (int it = 0; it < 32; ++it) wreg[it] = wsrc[it * 4 + kq]; // k = it*16+kq*4
    float c = 0.f;
    __syncthreads();

    for (int ts = 0; ts < T_LEN; ++ts) {
        float* hbuf = h_sh[ts & 1];
        if (tid < 64) {
            if (ts == 0) {
                float4 z = make_float4(0.f, 0.f, 0.f, 0.f);
                *(float4*)(hbuf + tid * 8) = z;
                *(float4*)(hbuf + tid * 8 + 4) = z;
            } else {
                int srow = dir ? (T_LEN - ts) : (ts - 1);
                const float* src = st + srow * 512 + tid * 8;
                v4f a, b;
                for (;;) {
                    llc_load8(src, a, b);
                    bool bad = a.x == 2.f || a.y == 2.f || a.z == 2.f || a.w == 2.f ||
                               b.x == 2.f || b.y == 2.f || b.z == 2.f || b.w == 2.f;
                    if (!bad) break;   // per-lane exit; wave reconverges
                }
                *(v4f*)(hbuf + tid * 8) = a;
                *(v4f*)(hbuf + tid * 8 + 4) = b;
            }
        }
        __syncthreads();

        const float4* hv = (const float4*)hbuf;
        float a0 = 0.f, a1 = 0.f, a2 = 0.f, a3 = 0.f;
#pragma unroll
        for (int it = 0; it < 32; ++it) {
            float4 h4 = hv[it * 4 + kq];
            float4 w4 = wreg[it];
            a0 += w4.x * h4.x; a1 += w4.y * h4.y;
            a2 += w4.z * h4.z; a3 += w4.w * h4.w;
        }
        float v = (a0 + a1) + (a2 + a3);
        v += __shfl_xor(v, 1, 4);
        v += __shfl_xor(v, 2, 4);
        float gi = __shfl(v, (u & 3) * 16 + 0, 64)  + gx_sh[ts * 64 + u];
        float gf = __shfl(v, (u & 3) * 16 + 4, 64)  + gx_sh[ts * 64 + 16 + u];
        float gg = __shfl(v, (u & 3) * 16 + 8, 64)  + gx_sh[ts * 64 + 32 + u];
        float go = __shfl(v, (u & 3) * 16 + 12, 64) + gx_sh[ts * 64 + 48 + u];
        float i_ = fsigmoid(gi);
        float f_ = fsigmoid(gf);
        float o_ = fsigmoid(go);
        c = f_ * c + i_ * ftanh(gg);
        float h = o_ * ftanh(c);
        if (r == 0) {   // lanes 0,16,32,48 of each wave: 4 dwords in one 64B line
            int drow = dir ? (T_LEN - 1 - ts) : ts;
            llc_store1(st + drow * 512 + w * 16 + u, h);
        }
    }
}

// ---------------- kernel 4: position tables  C[386,1024] = S[386,512] @ Wpart ----------------
// grid (16 n-tiles, 25 t-tiles of 16, 4 tables), block 256, 32KB LDS -> 5 blk/CU
__launch_bounds__(256, 5)
__global__ void k_tables(const float* __restrict__ fwd, const float* __restrict__ bwd,
                         const float* __restrict__ W1, const float* __restrict__ V1,
                         float* __restrict__ A, float* __restrict__ B,
                         float* __restrict__ AV, float* __restrict__ BV) {
    __shared__ float xs[16 * 512];
    int which = blockIdx.z;
    const float* S = (which & 1) ? bwd : fwd;
    const float* W = ((which >> 1) ? V1 : W1) + (which & 1) * 512 * 1024;
    float* out = which == 0 ? A : which == 1 ? B : which == 2 ? AV : BV;
    int nbase = blockIdx.x * 64, tbase = blockIdx.y * 16;
    int tid = threadIdx.x;

    for (int i = tid; i < 16 * 128; i += 256) {
        int row = i >> 7, c4 = i & 127;
        int t = tbase + row;
        float4 v = make_float4(0.f, 0.f, 0.f, 0.f);
        if (t < T_LEN) v = ((const float4*)(S + t * 512))[c4];
        ((float4*)xs)[i] = v;
    }
    __syncthreads();

    int cg = tid & 15;  // 16 col groups of 4
    int rg = tid >> 4;  // 16 rows (one per rg)
    int n = nbase + cg * 4;
    int t = tbase + rg;
    float4 acc = make_float4(0.f, 0.f, 0.f, 0.f);
    const float* xrow = xs + rg * 512;
#pragma unroll 4
    for (int k = 0; k < 512; ++k) {
        float4 wv = *(const float4*)(W + (long)k * 1024 + n);
        float x0 = xrow[k];
        acc.x += x0 * wv.x; acc.y += x0 * wv.y; acc.z += x0 * wv.z; acc.w += x0 * wv.w;
    }
    if (t < T_LEN) *(float4*)(out + (long)t * 1024 + n) = acc;
}

// ---------------- kernel 5: fused span FFN (R13-proven two-phase) ----------------
// grid NSPAN/64 blocks, 256 threads, ~26KB LDS -> 5 blocks/CU. Gather regs
// are consumed immediately (short live ranges; no cross-barrier staging).
#define TS 64
#define KC 32
__launch_bounds__(256, 5)
__global__ void k_span(const float* __restrict__ A, const float* __restrict__ B,
                       const float* __restrict__ AV, const float* __restrict__ BV,
                       const float* __restrict__ W2, const float* __restrict__ b1,
                       const float* __restrict__ b2, const float* __restrict__ V2,
                       const float* __restrict__ c1, const float* __restrict__ c2,
                       float* __restrict__ out) {
    __shared__ float hid[TS][KC + 4];
    __shared__ float w2s[KC * 128];
    __shared__ int ls[TS], rs[TS];
    int tid = threadIdx.x;
    int wg = blockIdx.x;

    if (tid < TS) {
        int s = wg * TS + tid;
        float disc = 769.0f * 769.0f - 8.0f * (float)s;
        int l = (int)floorf((769.0f - sqrtf(disc)) * 0.5f);
        if (l < 0) l = 0;
        if (l > 383) l = 383;
#define OFF(L) ((L) * 384 - ((L) * ((L) - 1)) / 2)
        while (l + 1 <= 384 && OFF(l + 1) <= s) ++l;
        while (l > 0 && OFF(l) > s) --l;
        int r = l + 1 + (s - OFF(l));
        ls[tid] = l; rs[tid] = r;
    }
    float acc[8][4];
#pragma unroll
    for (int a = 0; a < 8; ++a)
#pragma unroll
        for (int b = 0; b < 4; ++b) acc[a][b] = 0.f;
    float vacc[2] = {0.f, 0.f};
    int chg = tid & 31, sgm = tid >> 5;
    int kq = tid & 7, sgb = tid >> 3;
    __syncthreads();

    for (int kb = 0; kb < 1024; kb += KC) {
        if (kb) __syncthreads();
        for (int i = tid; i < KC * 128 / 4; i += 256)
            ((float4*)w2s)[i] = ((const float4*)(W2 + kb * 128))[i];
        int ko = kb + kq * 4;
        float4 bv = *(const float4*)(b1 + ko);
        float4 cv = *(const float4*)(c1 + ko);
        float4 v2 = *(const float4*)(V2 + ko);
#pragma unroll
        for (int si = 0; si < 2; ++si) {
            int sp = sgb * 2 + si;
            int l = ls[sp], r = rs[sp];
            float4 ar = *(const float4*)(A + (long)r * 1024 + ko);
            float4 al = *(const float4*)(A + (long)l * 1024 + ko);
            float4 bl = *(const float4*)(B + (long)(l + 1) * 1024 + ko);
            float4 br = *(const float4*)(B + (long)(r + 1) * 1024 + ko);
            float4 hx;
            hx.x = fmaxf(ar.x - al.x + bl.x - br.x + bv.x, 0.f);
            hx.y = fmaxf(ar.y - al.y + bl.y - br.y + bv.y, 0.f);
            hx.z = fmaxf(ar.z - al.z + bl.z - br.z + bv.z, 0.f);
            hx.w = fmaxf(ar.w - al.w + bl.w - br.w + bv.w, 0.f);
            *(float4*)&hid[sp][kq * 4] = hx;
            float4 vr = *(const float4*)(AV + (long)r * 1024 + ko);
            float4 vl = *(const float4*)(AV + (long)l * 1024 + ko);
            float4 ul = *(const float4*)(BV + (long)(l + 1) * 1024 + ko);
            float4 ur = *(const float4*)(BV + (long)(r + 1) * 1024 + ko);
            float h0 = fmaxf(vr.x - vl.x + ul.x - ur.x + cv.x, 0.f);
            float h1 = fmaxf(vr.y - vl.y + ul.y - ur.y + cv.y, 0.f);
            float h2 = fmaxf(vr.z - vl.z + ul.z - ur.z + cv.z, 0.f);
            float h3 = fmaxf(vr.w - vl.w + ul.w - ur.w + cv.w, 0.f);
            vacc[si] += h0 * v2.x + h1 * v2.y + h2 * v2.z + h3 * v2.w;
        }
        __syncthreads();
#pragma unroll 2
        for (int k = 0; k < KC; k += 4) {
            float4 h4[8];
#pragma unroll
            for (int j2 = 0; j2 < 8; ++j2)
                h4[j2] = *(const float4*)&hid[sgm * 8 + j2][k];
#pragma unroll
            for (int kk = 0; kk < 4; ++kk) {
                float4 wv = *(const float4*)&w2s[(k + kk) * 128 + chg * 4];
#pragma unroll
                for (int j2 = 0; j2 < 8; ++j2) {
                    float hx = (&h4[j2].x)[kk];
                    acc[j2][0] += hx * wv.x; acc[j2][1] += hx * wv.y;
                    acc[j2][2] += hx * wv.z; acc[j2][3] += hx * wv.w;
                }
            }
        }
    }

    float4 b2v = *(const float4*)(b2 + chg * 4);
#pragma unroll
    for (int j2 = 0; j2 < 8; ++j2) {
        int s = wg * TS + sgm * 8 + j2;
        float* o = out + (long)s * 129 + chg * 4;
        o[0] = acc[j2][0] + b2v.x; o[1] = acc[j2][1] + b2v.y;
        o[2] = acc[j2][2] + b2v.z; o[3] = acc[j2][3] + b2v.w;
    }
    float c2v = c2[0];
#pragma unroll
    for (int si = 0; si < 2; ++si) {
        float v = vacc[si];
        v += __shfl_xor(v, 4, 8);
        v += __shfl_xor(v, 2, 8);
        v += __shfl_xor(v, 1, 8);
        if (kq == 0) out[(long)(wg * TS + sgb * 2 + si) * 129 + 128] = v + c2v;
    }
}

extern "C" void kernel_launch(void* const* d_in, const int* in_sizes, int n_in,
                              void* d_out, int out_size, void* d_ws, size_t ws_size,
                              hipStream_t stream) {
    const int* tag_ids  = (const int*)d_in[0];
    const int* word_ids = (const int*)d_in[1];
    const float* tag_emb  = (const float*)d_in[2];
    const float* word_emb = (const float*)d_in[3];
    const float* Wf_ih = (const float*)d_in[4];
    const float* Wf_hh = (const float*)d_in[5];
    const float* bf    = (const float*)d_in[6];
    const float* Wb_ih = (const float*)d_in[7];
    const float* Wb_hh = (const float*)d_in[8];
    const float* bb    = (const float*)d_in[9];
    const float* W1 = (const float*)d_in[10];
    const float* b1 = (const float*)d_in[11];
    const float* W2 = (const float*)d_in[12];
    const float* b2 = (const float*)d_in[13];
    const float* V1 = (const float*)d_in[14];
    const float* c1 = (const float*)d_in[15];
    const float* V2 = (const float*)d_in[16];
    const float* c2 = (const float*)d_in[17];

    float* ws = (float*)d_ws;
    float* x   = ws + 256;
    float* gxf = x + T_LEN * 512;
    float* gxb = gxf + T_LEN * 2048;
    float* fwd = gxb + T_LEN * 2048;
    float* bwd = fwd + T_LEN * 512;   // contiguous after fwd (poisoned together)
    float* A   = bwd + T_LEN * 512;
    float* B   = A + T_LEN * 1024;
    float* AV  = B + T_LEN * 1024;
    float* BV  = AV + T_LEN * 1024;

    k_embed<<<T_LEN, 128, 0, stream>>>(tag_ids, word_ids, tag_emb, word_emb, x, fwd);
    k_gx<<<dim3(32, 25, 2), 256, 0, stream>>>(x, Wf_ih, bf, Wb_ih, bb, gxf, gxb);
    k_scan<<<64, 256, 0, stream>>>(gxf, gxb, Wf_hh, Wb_hh, fwd, bwd);
    k_tables<<<dim3(16, 25, 4), 256, 0, stream>>>(fwd, bwd, W1, V1, A, B, AV, BV);
    k_span<<<NSPAN / 64, 256, 0, stream>>>(A, B, AV, BV, W2, b1, b2, V2, c1, c2,
                                           (float*)d_out);
}

// Round 17
// 1346.431 us; speedup vs baseline: 1.0704x; 1.0704x over previous
//
#include <hip/hip_runtime.h>

#define T_LEN 386
#define NSPAN 73920

typedef float v4f __attribute__((ext_vector_type(4)));

// ---- LLC ops (sc0 sc1: device scope) ----
__device__ inline void llc_load8(const float* p, v4f& a, v4f& b) {
    asm volatile("global_load_dwordx4 %0, %2, off sc0 sc1\n\t"
                 "global_load_dwordx4 %1, %2, off offset:16 sc0 sc1\n\t"
                 "s_waitcnt vmcnt(0)"
                 : "=&v"(a), "=&v"(b) : "v"(p) : "memory");
}
__device__ inline void llc_store1(float* p, float v) {
    asm volatile("global_store_dword %0, %1, off sc0 sc1"
                 :: "v"(p), "v"(v) : "memory");
}

__device__ inline float fsigmoid(float x) { return 1.f / (1.f + __expf(-x)); }
__device__ inline float ftanh(float x) {
    x = fminf(fmaxf(x, -15.f), 15.f);
    float e = __expf(2.f * x);
    return (e - 1.f) / (e + 1.f);
}

// ---------------- kernel 1: embedding concat + h-sentinel poison ----------------
// grid 386, 128 threads. Also poisons fwd/bwd (2*386*512 floats) with the
// unreachable sentinel 2.0f (h = o*tanh(c) is strictly inside (-1,1)):
// 386*128 threads * 8 floats = 395264 = 2*386*512 exactly.
__global__ void k_embed(const int* __restrict__ tag_ids, const int* __restrict__ word_ids,
                        const float* __restrict__ tag_emb, const float* __restrict__ word_emb,
                        float* __restrict__ x, float* __restrict__ st) {
    int t = blockIdx.x;
    int tid = threadIdx.x; // 128
    long pbase = ((long)t * 128 + tid) * 8;
#pragma unroll
    for (int j = 0; j < 8; ++j)
        __hip_atomic_store(st + pbase + j, 2.0f, __ATOMIC_RELAXED,
                           __HIP_MEMORY_SCOPE_AGENT);
    int tr = tag_ids[t], wr = word_ids[t];
    x[t * 512 + tid] = tag_emb[tr * 128 + tid];
    for (int j = tid; j < 384; j += 128)
        x[t * 512 + 128 + j] = word_emb[wr * 384 + j];
}

// ---------------- kernel 2: gx = x(rev) @ Wih^T + b ----------------
// grid (32 n-tiles, 25 t-tiles of 16, 2 dirs), block 256, 32KB LDS -> 4 blk/CU
__global__ void k_gx(const float* __restrict__ x,
                     const float* __restrict__ Wf, const float* __restrict__ bf,
                     const float* __restrict__ Wb, const float* __restrict__ bb,
                     float* __restrict__ gxf, float* __restrict__ gxb) {
    __shared__ float xs[16 * 512];
    int dir = blockIdx.z;
    const float* W = dir ? Wb : Wf;
    const float* bias = dir ? bb : bf;
    float* out = dir ? gxb : gxf;
    int nbase = blockIdx.x * 64;
    int tbase = blockIdx.y * 16;
    int tid = threadIdx.x;

    for (int i = tid; i < 16 * 128; i += 256) { // float4 units
        int row = i >> 7, c4 = i & 127;
        int t = tbase + row;
        float4 v = make_float4(0.f, 0.f, 0.f, 0.f);
        if (t < T_LEN) {
            int src = dir ? (T_LEN - 1 - t) : t;
            v = ((const float4*)(x + src * 512))[c4];
        }
        ((float4*)xs)[i] = v;
    }
    __syncthreads();

    int col = tid >> 2; // 0..63
    int kq = tid & 3;
    int n = nbase + col;
    const float4* wrow = (const float4*)(W + (long)n * 512);
    float acc[16];
#pragma unroll
    for (int r = 0; r < 16; ++r) acc[r] = 0.f;
#pragma unroll 2
    for (int it = 0; it < 32; ++it) {
        int k4 = it * 4 + kq; // k = it*16 + kq*4
        float4 w = wrow[k4];
#pragma unroll
        for (int r = 0; r < 16; ++r) {
            float4 xv = ((const float4*)(xs + r * 512))[k4];
            acc[r] += w.x * xv.x + w.y * xv.y + w.z * xv.z + w.w * xv.w;
        }
    }
#pragma unroll
    for (int r = 0; r < 16; ++r) {
        float v = acc[r];
        v += __shfl_xor(v, 1, 4);
        v += __shfl_xor(v, 2, 4);
        acc[r] = v;
    }
    if (kq == 0) {
        float bv = bias[n];
        for (int r = 0; r < 16; ++r) {
            int t = tbase + r;
            if (t < T_LEN) out[t * 2048 + n] = acc[r] + bv;
        }
    }
}

// ---------------- kernel 3: persistent bidirectional LSTM scan (proven) ----------------
// grid 64 (2 dirs * 32 WGs), block 256, 1 WG/CU. Each WG owns 16 hidden units;
// a 16-lane group owns one unit (4 gates x 4 k-slices); Whh slice in regs,
// gx slice in LDS, cell state in regs. Cross-WG broadcast: data-as-flag
// (sentinel 2.0f) through the LLC. Measured floor: ~2.25us/step (LLC
// store->load visibility); XCD-L2 fast paths all failed on HW (R5/R7/R12).
__launch_bounds__(256, 1)
__global__ void k_scan(const float* __restrict__ gxf, const float* __restrict__ gxb,
                       const float* __restrict__ Wfhh, const float* __restrict__ Wbhh,
                       float* fwd, float* bwd) {
    __shared__ float gx_sh[T_LEN * 64];
    __shared__ float h_sh[2][512];
    int bid = blockIdx.x;
    int dir = bid >> 5;
    int w = bid & 31;
    int tid = threadIdx.x;
    const float* gx = dir ? gxb : gxf;
    const float* Whh = dir ? Wbhh : Wfhh;
    float* st = dir ? bwd : fwd;

    for (int idx = tid; idx < T_LEN * 64; idx += 256) {
        int t = idx >> 6, j = idx & 63;
        gx_sh[idx] = gx[t * 2048 + (j >> 4) * 512 + w * 16 + (j & 15)];
    }

    int u = tid >> 4;  // hidden unit 0..15
    int r = tid & 15;  // lane-in-unit
    int g = r >> 2;    // gate 0..3 (i,f,g,o)
    int kq = r & 3;    // k-slice
    int grow = g * 512 + w * 16 + u;
    float4 wreg[32];
    const float4* wsrc = (const float4*)(Whh + (long)grow * 512);
#pragma unroll
    for (int it = 0; it < 32; ++it) wreg[it] = wsrc[it * 4 + kq]; // k = it*16+kq*4
    float c = 0.f;
    __syncthreads();

    for (int ts = 0; ts < T_LEN; ++ts) {
        float* hbuf = h_sh[ts & 1];
        if (tid < 64) {
            if (ts == 0) {
                float4 z = make_float4(0.f, 0.f, 0.f, 0.f);
                *(float4*)(hbuf + tid * 8) = z;
                *(float4*)(hbuf + tid * 8 + 4) = z;
            } else {
                int srow = dir ? (T_LEN - ts) : (ts - 1);
                const float* src = st + srow * 512 + tid * 8;
                v4f a, b;
                for (;;) {
                    llc_load8(src, a, b);
                    bool bad = a.x == 2.f || a.y == 2.f || a.z == 2.f || a.w == 2.f ||
                               b.x == 2.f || b.y == 2.f || b.z == 2.f || b.w == 2.f;
                    if (!bad) break;   // per-lane exit; wave reconverges
                }
                *(v4f*)(hbuf + tid * 8) = a;
                *(v4f*)(hbuf + tid * 8 + 4) = b;
            }
        }
        __syncthreads();

        const float4* hv = (const float4*)hbuf;
        float a0 = 0.f, a1 = 0.f, a2 = 0.f, a3 = 0.f;
#pragma unroll
        for (int it = 0; it < 32; ++it) {
            float4 h4 = hv[it * 4 + kq];
            float4 w4 = wreg[it];
            a0 += w4.x * h4.x; a1 += w4.y * h4.y;
            a2 += w4.z * h4.z; a3 += w4.w * h4.w;
        }
        float v = (a0 + a1) + (a2 + a3);
        v += __shfl_xor(v, 1, 4);
        v += __shfl_xor(v, 2, 4);
        float gi = __shfl(v, (u & 3) * 16 + 0, 64)  + gx_sh[ts * 64 + u];
        float gf = __shfl(v, (u & 3) * 16 + 4, 64)  + gx_sh[ts * 64 + 16 + u];
        float gg = __shfl(v, (u & 3) * 16 + 8, 64)  + gx_sh[ts * 64 + 32 + u];
        float go = __shfl(v, (u & 3) * 16 + 12, 64) + gx_sh[ts * 64 + 48 + u];
        float i_ = fsigmoid(gi);
        float f_ = fsigmoid(gf);
        float o_ = fsigmoid(go);
        c = f_ * c + i_ * ftanh(gg);
        float h = o_ * ftanh(c);
        if (r == 0) {   // lanes 0,16,32,48 of each wave: 4 dwords in one 64B line
            int drow = dir ? (T_LEN - 1 - ts) : ts;
            llc_store1(st + drow * 512 + w * 16 + u, h);
        }
    }
}

// ---------------- kernel 4: position tables  C[386,1024] = S[386,512] @ Wpart ----------------
// grid (16 n-tiles, 25 t-tiles of 16, 4 tables), block 256, 32KB LDS -> 4 blk/CU
__global__ void k_tables(const float* __restrict__ fwd, const float* __restrict__ bwd,
                         const float* __restrict__ W1, const float* __restrict__ V1,
                         float* __restrict__ A, float* __restrict__ B,
                         float* __restrict__ AV, float* __restrict__ BV) {
    __shared__ float xs[16 * 512];
    int which = blockIdx.z;
    const float* S = (which & 1) ? bwd : fwd;
    const float* W = ((which >> 1) ? V1 : W1) + (which & 1) * 512 * 1024;
    float* out = which == 0 ? A : which == 1 ? B : which == 2 ? AV : BV;
    int nbase = blockIdx.x * 64, tbase = blockIdx.y * 16;
    int tid = threadIdx.x;

    for (int i = tid; i < 16 * 128; i += 256) {
        int row = i >> 7, c4 = i & 127;
        int t = tbase + row;
        float4 v = make_float4(0.f, 0.f, 0.f, 0.f);
        if (t < T_LEN) v = ((const float4*)(S + t * 512))[c4];
        ((float4*)xs)[i] = v;
    }
    __syncthreads();

    int cg = tid & 15;  // 16 col groups of 4
    int rg = tid >> 4;  // 16 rows (one per rg)
    int n = nbase + cg * 4;
    int t = tbase + rg;
    float4 acc = make_float4(0.f, 0.f, 0.f, 0.f);
    const float* xrow = xs + rg * 512;
#pragma unroll 4
    for (int k = 0; k < 512; ++k) {
        float4 wv = *(const float4*)(W + (long)k * 1024 + n);
        float x0 = xrow[k];
        acc.x += x0 * wv.x; acc.y += x0 * wv.y; acc.z += x0 * wv.z; acc.w += x0 * wv.w;
    }
    if (t < T_LEN) *(float4*)(out + (long)t * 1024 + n) = acc;
}

// ---------------- kernel 5: fused span FFN (R13-proven two-phase) ----------------
// grid NSPAN/64 blocks, 256 threads, ~26KB LDS -> 4 blocks/CU. Gather regs
// are consumed immediately (short live ranges; no cross-barrier staging).
#define TS 64
#define KC 32
__launch_bounds__(256, 4)
__global__ void k_span(const float* __restrict__ A, const float* __restrict__ B,
                       const float* __restrict__ AV, const float* __restrict__ BV,
                       const float* __restrict__ W2, const float* __restrict__ b1,
                       const float* __restrict__ b2, const float* __restrict__ V2,
                       const float* __restrict__ c1, const float* __restrict__ c2,
                       float* __restrict__ out) {
    __shared__ float hid[TS][KC + 4];
    __shared__ float w2s[KC * 128];
    __shared__ int ls[TS], rs[TS];
    int tid = threadIdx.x;
    int wg = blockIdx.x;

    if (tid < TS) {
        int s = wg * TS + tid;
        float disc = 769.0f * 769.0f - 8.0f * (float)s;
        int l = (int)floorf((769.0f - sqrtf(disc)) * 0.5f);
        if (l < 0) l = 0;
        if (l > 383) l = 383;
#define OFF(L) ((L) * 384 - ((L) * ((L) - 1)) / 2)
        while (l + 1 <= 384 && OFF(l + 1) <= s) ++l;
        while (l > 0 && OFF(l) > s) --l;
        int r = l + 1 + (s - OFF(l));
        ls[tid] = l; rs[tid] = r;
    }
    float acc[8][4];
#pragma unroll
    for (int a = 0; a < 8; ++a)
#pragma unroll
        for (int b = 0; b < 4; ++b) acc[a][b] = 0.f;
    float vacc[2] = {0.f, 0.f};
    int chg = tid & 31, sgm = tid >> 5;
    int kq = tid & 7, sgb = tid >> 3;
    __syncthreads();

    for (int kb = 0; kb < 1024; kb += KC) {
        if (kb) __syncthreads();
        for (int i = tid; i < KC * 128 / 4; i += 256)
            ((float4*)w2s)[i] = ((const float4*)(W2 + kb * 128))[i];
        int ko = kb + kq * 4;
        float4 bv = *(const float4*)(b1 + ko);
        float4 cv = *(const float4*)(c1 + ko);
        float4 v2 = *(const float4*)(V2 + ko);
#pragma unroll
        for (int si = 0; si < 2; ++si) {
            int sp = sgb * 2 + si;
            int l = ls[sp], r = rs[sp];
            float4 ar = *(const float4*)(A + (long)r * 1024 + ko);
            float4 al = *(const float4*)(A + (long)l * 1024 + ko);
            float4 bl = *(const float4*)(B + (long)(l + 1) * 1024 + ko);
            float4 br = *(const float4*)(B + (long)(r + 1) * 1024 + ko);
            float4 hx;
            hx.x = fmaxf(ar.x - al.x + bl.x - br.x + bv.x, 0.f);
            hx.y = fmaxf(ar.y - al.y + bl.y - br.y + bv.y, 0.f);
            hx.z = fmaxf(ar.z - al.z + bl.z - br.z + bv.z, 0.f);
            hx.w = fmaxf(ar.w - al.w + bl.w - br.w + bv.w, 0.f);
            *(float4*)&hid[sp][kq * 4] = hx;
            float4 vr = *(const float4*)(AV + (long)r * 1024 + ko);
            float4 vl = *(const float4*)(AV + (long)l * 1024 + ko);
            float4 ul = *(const float4*)(BV + (long)(l + 1) * 1024 + ko);
            float4 ur = *(const float4*)(BV + (long)(r + 1) * 1024 + ko);
            float h0 = fmaxf(vr.x - vl.x + ul.x - ur.x + cv.x, 0.f);
            float h1 = fmaxf(vr.y - vl.y + ul.y - ur.y + cv.y, 0.f);
            float h2 = fmaxf(vr.z - vl.z + ul.z - ur.z + cv.z, 0.f);
            float h3 = fmaxf(vr.w - vl.w + ul.w - ur.w + cv.w, 0.f);
            vacc[si] += h0 * v2.x + h1 * v2.y + h2 * v2.z + h3 * v2.w;
        }
        __syncthreads();
#pragma unroll 2
        for (int k = 0; k < KC; k += 4) {
            float4 h4[8];
#pragma unroll
            for (int j2 = 0; j2 < 8; ++j2)
                h4[j2] = *(const float4*)&hid[sgm * 8 + j2][k];
#pragma unroll
            for (int kk = 0; kk < 4; ++kk) {
                float4 wv = *(const float4*)&w2s[(k + kk) * 128 + chg * 4];
#pragma unroll
                for (int j2 = 0; j2 < 8; ++j2) {
                    float hx = (&h4[j2].x)[kk];
                    acc[j2][0] += hx * wv.x; acc[j2][1] += hx * wv.y;
                    acc[j2][2] += hx * wv.z; acc[j2][3] += hx * wv.w;
                }
            }
        }
    }

    float4 b2v = *(const float4*)(b2 + chg * 4);
#pragma unroll
    for (int j2 = 0; j2 < 8; ++j2) {
        int s = wg * TS + sgm * 8 + j2;
        float* o = out + (long)s * 129 + chg * 4;
        o[0] = acc[j2][0] + b2v.x; o[1] = acc[j2][1] + b2v.y;
        o[2] = acc[j2][2] + b2v.z; o[3] = acc[j2][3] + b2v.w;
    }
    float c2v = c2[0];
#pragma unroll
    for (int si = 0; si < 2; ++si) {
        float v = vacc[si];
        v += __shfl_xor(v, 4, 8);
        v += __shfl_xor(v, 2, 8);
        v += __shfl_xor(v, 1, 8);
        if (kq == 0) out[(long)(wg * TS + sgb * 2 + si) * 129 + 128] = v + c2v;
    }
}

extern "C" void kernel_launch(void* const* d_in, const int* in_sizes, int n_in,
                              void* d_out, int out_size, void* d_ws, size_t ws_size,
                              hipStream_t stream) {
    const int* tag_ids  = (const int*)d_in[0];
    const int* word_ids = (const int*)d_in[1];
    const float* tag_emb  = (const float*)d_in[2];
    const float* word_emb = (const float*)d_in[3];
    const float* Wf_ih = (const float*)d_in[4];
    const float* Wf_hh = (const float*)d_in[5];
    const float* bf    = (const float*)d_in[6];
    const float* Wb_ih = (const float*)d_in[7];
    const float* Wb_hh = (const float*)d_in[8];
    const float* bb    = (const float*)d_in[9];
    const float* W1 = (const float*)d_in[10];
    const float* b1 = (const float*)d_in[11];
    const float* W2 = (const float*)d_in[12];
    const float* b2 = (const float*)d_in[13];
    const float* V1 = (const float*)d_in[14];
    const float* c1 = (const float*)d_in[15];
    const float* V2 = (const float*)d_in[16];
    const float* c2 = (const float*)d_in[17];

    float* ws = (float*)d_ws;
    float* x   = ws + 256;
    float* gxf = x + T_LEN * 512;
    float* gxb = gxf + T_LEN * 2048;
    float* fwd = gxb + T_LEN * 2048;
    float* bwd = fwd + T_LEN * 512;   // contiguous after fwd (poisoned together)
    float* A   = bwd + T_LEN * 512;
    float* B   = A + T_LEN * 1024;
    float* AV  = B + T_LEN * 1024;
    float* BV  = AV + T_LEN * 1024;

    k_embed<<<T_LEN, 128, 0, stream>>>(tag_ids, word_ids, tag_emb, word_emb, x, fwd);
    k_gx<<<dim3(32, 25, 2), 256, 0, stream>>>(x, Wf_ih, bf, Wb_ih, bb, gxf, gxb);
    k_scan<<<64, 256, 0, stream>>>(gxf, gxb, Wf_hh, Wb_hh, fwd, bwd);
    k_tables<<<dim3(16, 25, 4), 256, 0, stream>>>(fwd, bwd, W1, V1, A, B, AV, BV);
    k_span<<<NSPAN / 64, 256, 0, stream>>>(A, B, AV, BV, W2, b1, b2, V2, c1, c2,
                                           (float*)d_out);
}